// Round 9
// baseline (192.717 us; speedup 1.0000x reference)
//
#include <hip/hip_runtime.h>
#include <hip/hip_cooperative_groups.h>
#include <math.h>

namespace cg = cooperative_groups;
typedef unsigned long long u64;

#define H 2048
#define W 2048
#define NWR 64          // word-rows (H/32)
#define HALO 128
#define TILE 256
#define LW 512          // TILE + 2*HALO
#define DCLAMP 2900     // > max possible distance; f <= 8.41e6 exact in fp32
#define NBLK 512
#define NTHR 256

// ---------------------------------------------------------------------------
// Vertical distance from the background bitmask. rmask[kw][j] bit i = row
// 32*kw+i is background. 96-bit window covers >= +/-32 rows; rare far-walk
// beyond (P ~ 2^-32 per pixel for this input, exact for any input).
// ---------------------------------------------------------------------------
__device__ __forceinline__ int vfar_up(const unsigned* __restrict__ rmask, int col, int r, int ks) {
    for (int kk = ks - 2; kk >= 0; --kk) {
        unsigned w = rmask[(size_t)kk * W + col];
        if (w) return r - (kk * 32 + (31 - __clz(w)));
    }
    return DCLAMP;
}
__device__ __forceinline__ int vfar_dn(const unsigned* __restrict__ rmask, int col, int r, int ks) {
    for (int kk = ks + 2; kk < NWR; ++kk) {
        unsigned w = rmask[(size_t)kk * W + col];
        if (w) return (kk * 32 + (__ffs(w) - 1)) - r;
    }
    return DCLAMP;
}

// exact f at arbitrary (r, col) straight from the bitmask (rare fallback path)
__device__ float f_from_mask(const unsigned* __restrict__ rmask, int col, int r) {
    int kw = r >> 5, b = r & 31;
    unsigned wm1 = (kw > 0)       ? rmask[(size_t)(kw - 1) * W + col] : 0u;
    unsigned w0  =                  rmask[(size_t)kw * W + col];
    unsigned wp1 = (kw < NWR - 1) ? rmask[(size_t)(kw + 1) * W + col] : 0u;
    if ((w0 >> b) & 1u) return 0.0f;
    u64 A  = (u64)wm1 | ((u64)w0 << 32);
    u64 Bv = (u64)w0  | ((u64)wp1 << 32);
    int p = 32 + b;
    u64 Am = A & ((1ull << p) - 1ull);
    int da = Am ? (p - (63 - __clzll(Am))) : vfar_up(rmask, col, r, kw);
    u64 Bm = Bv >> (b + 1);
    int db = Bm ? __ffsll(Bm) : vfar_dn(rmask, col, r, kw);
    int d1 = min(min(da, db), DCLAMP);
    return (float)d1 * (float)d1;
}

// ---------------------------------------------------------------------------
// P1: pack background bits. gid -> (word-row kw, col). All loads/stores coalesced.
// ---------------------------------------------------------------------------
__device__ __forceinline__ void pack_word(const float* __restrict__ img,
                                          unsigned* __restrict__ rmask, int gid) {
    int col = gid & (W - 1);
    int kw  = gid >> 11;
    unsigned w = 0;
#pragma unroll 8
    for (int i = 0; i < 32; ++i)
        w |= (img[(size_t)(kw * 32 + i) * W + col] <= 0.5f ? 1u : 0u) << i;
    rmask[(size_t)kw * W + col] = w;
}

// ---------------------------------------------------------------------------
// Core: block (tx = col-tile, ks = word-row) computes f for its 32x512 window
// into LDS from the bitmask, then the exact early-exit row pass for its
// 32x256 output tile. res[32] per thread; returns thread-local max.
// Early-exit exact: candidates at offset d cost >= d^2; stop at d*d >= best.
// ---------------------------------------------------------------------------
__device__ float block_edt(const unsigned* __restrict__ rmask,
                           float (*ftile)[LW], float* res, int blk, int tid) {
    const int tx = blk & 7, ks = blk >> 3;
    const int c0 = tx * TILE;
    const int rbase = ks * 32;
    {
        int lc = tid * 2;
        int gc = c0 - HALO + lc;
        if (gc >= 0 && gc < W) {
            uint2 wm1 = (ks > 0)       ? *(const uint2*)(rmask + (size_t)(ks - 1) * W + gc) : make_uint2(0u, 0u);
            uint2 w0  =                  *(const uint2*)(rmask + (size_t)ks * W + gc);
            uint2 wp1 = (ks < NWR - 1) ? *(const uint2*)(rmask + (size_t)(ks + 1) * W + gc) : make_uint2(0u, 0u);
            u64 A0  = (u64)wm1.x | ((u64)w0.x << 32);
            u64 B0  = (u64)w0.x  | ((u64)wp1.x << 32);
            u64 A1  = (u64)wm1.y | ((u64)w0.y << 32);
            u64 B1  = (u64)w0.y  | ((u64)wp1.y << 32);
#pragma unroll 8
            for (int i = 0; i < 32; ++i) {
                int p = 32 + i, r = rbase + i;
                u64 pm = (1ull << p) - 1ull;
                // col gc
                u64 Am = A0 & pm;
                int da = Am ? (p - (63 - __clzll(Am))) : vfar_up(rmask, gc, r, ks);
                u64 Bm = B0 >> (i + 1);
                int db = Bm ? __ffsll(Bm) : vfar_dn(rmask, gc, r, ks);
                int d1 = min(min(da, db), DCLAMP);
                float f0 = ((w0.x >> i) & 1u) ? 0.0f : (float)d1 * (float)d1;
                // col gc+1
                Am = A1 & pm;
                da = Am ? (p - (63 - __clzll(Am))) : vfar_up(rmask, gc + 1, r, ks);
                Bm = B1 >> (i + 1);
                db = Bm ? __ffsll(Bm) : vfar_dn(rmask, gc + 1, r, ks);
                d1 = min(min(da, db), DCLAMP);
                float f1 = ((w0.y >> i) & 1u) ? 0.0f : (float)d1 * (float)d1;
                *(float2*)&ftile[i][lc] = make_float2(f0, f1);
            }
        } else {
#pragma unroll 8
            for (int i = 0; i < 32; ++i)
                *(float2*)&ftile[i][lc] = make_float2(1e9f, 1e9f);  // pad: never wins
        }
    }
    __syncthreads();

    const int jj = c0 + tid;
    const int lj = HALO + tid;   // lj +/- HALO stays in [0, 511]
    float lmax = 0.0f;
    for (int i = 0; i < 32; ++i) {
        float best = ftile[i][lj];
        for (int d = 1; d <= HALO && (float)(d * d) < best; ++d) {
            float q = (float)(d * d);
            best = fminf(best, ftile[i][lj - d] + q);
            best = fminf(best, ftile[i][lj + d] + q);
        }
        if ((float)((HALO + 1) * (HALO + 1)) < best) {
            // exact beyond-halo fallback (never taken for random 50% mask)
            int r = rbase + i;
            for (int d = HALO + 1; d < W && (float)(d * d) < best; ++d) {
                float q = (float)(d * d);
                int jm = jj - d, jp = jj + d;
                if (jm >= 0) best = fminf(best, f_from_mask(rmask, jm, r) + q);
                if (jp < W)  best = fminf(best, f_from_mask(rmask, jp, r) + q);
            }
        }
        float rr = sqrtf(best);
        res[i] = rr;
        lmax = fmaxf(lmax, rr);
    }
    return lmax;
}

// ---------------------------------------------------------------------------
// Cooperative single-launch kernel: pack -> sync -> EDT (res in regs, max
// atomic) -> sync -> normalize + single int32 write (uint8 semantics).
// ---------------------------------------------------------------------------
__global__ void __launch_bounds__(NTHR, 2)
edt_coop(const float* __restrict__ img, int* __restrict__ out,
         unsigned* __restrict__ rmask, unsigned int* __restrict__ maxp) {
    cg::grid_group grid = cg::this_grid();
    __shared__ float ftile[32][LW];   // 64 KB
    __shared__ float smax[4];
    const int tid = threadIdx.x, blk = blockIdx.x;
    if (blk == 0 && tid == 0) *maxp = 0u;

    pack_word(img, rmask, blk * NTHR + tid);
    grid.sync();

    float res[32];
    float lmax = block_edt(rmask, ftile, res, blk, tid);
    for (int o = 32; o > 0; o >>= 1) lmax = fmaxf(lmax, __shfl_down(lmax, o, 64));
    if ((tid & 63) == 0) smax[tid >> 6] = lmax;
    __syncthreads();
    if (tid == 0)
        atomicMax(maxp, __float_as_uint(fmaxf(fmaxf(smax[0], smax[1]),
                                              fmaxf(smax[2], smax[3]))));
    grid.sync();

    float m = __uint_as_float(*maxp);
    const int jj = (blk & 7) * TILE + tid;
    const int rbase = (blk >> 3) * 32;
    for (int i = 0; i < 32; ++i) {
        float dv = res[i];
        float v = (m > 0.0f) ? (dv / m * 255.0f) : dv;  // numpy op order
        v = fminf(fmaxf(v, 0.0f), 255.0f);
        out[(size_t)(rbase + i) * W + jj] = (int)v;     // trunc, like astype(uint8)
    }
}

// --------------------- non-coop fallback (same phases) ----------------------
__global__ void fb_pack(const float* __restrict__ img, unsigned* __restrict__ rmask,
                        unsigned int* __restrict__ maxp) {
    int gid = blockIdx.x * NTHR + threadIdx.x;
    if (gid == 0) *maxp = 0u;
    pack_word(img, rmask, gid);
}
__global__ void __launch_bounds__(NTHR, 2)
fb_main(const unsigned* __restrict__ rmask, float* __restrict__ dist,
        unsigned int* __restrict__ maxp) {
    __shared__ float ftile[32][LW];
    __shared__ float smax[4];
    const int tid = threadIdx.x, blk = blockIdx.x;
    float res[32];
    float lmax = block_edt(rmask, ftile, res, blk, tid);
    const int jj = (blk & 7) * TILE + tid;
    const int rbase = (blk >> 3) * 32;
    for (int i = 0; i < 32; ++i)
        dist[(size_t)(rbase + i) * W + jj] = res[i];
    for (int o = 32; o > 0; o >>= 1) lmax = fmaxf(lmax, __shfl_down(lmax, o, 64));
    if ((tid & 63) == 0) smax[tid >> 6] = lmax;
    __syncthreads();
    if (tid == 0)
        atomicMax(maxp, __float_as_uint(fmaxf(fmaxf(smax[0], smax[1]),
                                              fmaxf(smax[2], smax[3]))));
}
__global__ void fb_norm(int* __restrict__ out, const unsigned int* __restrict__ maxp) {
    size_t idx = ((size_t)blockIdx.x * NTHR + threadIdx.x) * 4;
    float m = __uint_as_float(*maxp);
    float4 dv = *(const float4*)((const float*)out + idx);
    float r[4] = {dv.x, dv.y, dv.z, dv.w};
    int o[4];
#pragma unroll
    for (int k = 0; k < 4; ++k) {
        float v = (m > 0.0f) ? (r[k] / m * 255.0f) : r[k];
        v = fminf(fmaxf(v, 0.0f), 255.0f);
        o[k] = (int)v;
    }
    *(int4*)(out + idx) = make_int4(o[0], o[1], o[2], o[3]);
}

extern "C" void kernel_launch(void* const* d_in, const int* in_sizes, int n_in,
                              void* d_out, int out_size, void* d_ws, size_t ws_size,
                              hipStream_t stream) {
    const float* img = (const float*)d_in[0];
    int* out = (int*)d_out;

    // ws: rmask 512 KB | maxp 4 B
    char* ws = (char*)d_ws;
    unsigned* rmask = (unsigned*)ws;
    unsigned int* maxp = (unsigned int*)(ws + (size_t)NWR * W * 4);

    void* args[] = {(void*)&img, (void*)&out, (void*)&rmask, (void*)&maxp};
    hipError_t e = hipLaunchCooperativeKernel((const void*)edt_coop, dim3(NBLK),
                                              dim3(NTHR), args, 0, stream);
    if (e != hipSuccess) {
        // deterministic fallback: same phases, plain launches
        fb_pack<<<dim3(NBLK), dim3(NTHR), 0, stream>>>(img, rmask, maxp);
        fb_main<<<dim3(NBLK), dim3(NTHR), 0, stream>>>(rmask, (float*)out, maxp);
        fb_norm<<<dim3(H * W / (NTHR * 4)), dim3(NTHR), 0, stream>>>(out, maxp);
    }
}

// Round 10
// 93.822 us; speedup vs baseline: 2.0541x; 2.0541x over previous
//
#include <hip/hip_runtime.h>
#include <math.h>

typedef unsigned long long u64;

#define H 2048
#define W 2048
#define NWR 64          // word-rows (H/32)
#define TILE 128        // output cols per K2 block
#define HALO 32         // LDS halo; early-exit covers d<=HALO, then global path
#define LW (TILE + 2 * HALO)   // 192
#define DCLAMP 2900     // > max possible distance; f <= 8.41e6 exact in fp32
#define NTHR 256

// ---------------------------------------------------------------------------
// Far-walks on the background bitmask (rare: only when a column has no
// background within the 96-bit window). Exact for any input.
// ---------------------------------------------------------------------------
__device__ __forceinline__ int vfar_up(const unsigned* __restrict__ rmask, int col, int r, int ks) {
    for (int kk = ks - 2; kk >= 0; --kk) {
        unsigned w = rmask[kk * W + col];
        if (w) return r - (kk * 32 + (31 - __clz(w)));
    }
    return DCLAMP;
}
__device__ __forceinline__ int vfar_dn(const unsigned* __restrict__ rmask, int col, int r, int ks) {
    for (int kk = ks + 2; kk < NWR; ++kk) {
        unsigned w = rmask[kk * W + col];
        if (w) return (kk * 32 + (__ffs(w) - 1)) - r;
    }
    return DCLAMP;
}

// exact f at arbitrary (r, col) straight from the bitmask (never-taken fallback)
__device__ float f_from_mask(const unsigned* __restrict__ rmask, int col, int r) {
    int kw = r >> 5, b = r & 31;
    unsigned wm1 = (kw > 0)       ? rmask[(kw - 1) * W + col] : 0u;
    unsigned w0  =                  rmask[kw * W + col];
    unsigned wp1 = (kw < NWR - 1) ? rmask[(kw + 1) * W + col] : 0u;
    if ((w0 >> b) & 1u) return 0.0f;
    u64 A  = (u64)wm1 | ((u64)w0 << 32);
    u64 Bv = (u64)w0  | ((u64)wp1 << 32);
    int p = 32 + b;
    u64 Am = A & ((1ull << p) - 1ull);
    int da = Am ? (p - (63 - __clzll(Am))) : vfar_up(rmask, col, r, kw);
    u64 Bm = Bv >> (b + 1);
    int db = Bm ? __ffsll(Bm) : vfar_dn(rmask, col, r, kw);
    int d1 = min(min(da, db), DCLAMP);
    return (float)d1 * (float)d1;
}

// ---------------------------------------------------------------------------
// K1: pack background bits. One thread per (word-row, col) word; coalesced.
// Thread 0 zero-inits maxp (stream-ordered before K2's atomics).
// ---------------------------------------------------------------------------
__global__ void k1_pack(const float* __restrict__ img, unsigned* __restrict__ rmask,
                        unsigned int* __restrict__ maxp) {
    int gid = blockIdx.x * NTHR + threadIdx.x;
    if (gid == 0) *maxp = 0u;
    int col = gid & (W - 1);
    int kw  = gid >> 11;
    unsigned w = 0;
#pragma unroll
    for (int i = 0; i < 32; ++i)
        w |= (img[(size_t)(kw * 32 + i) * W + col] <= 0.5f ? 1u : 0u) << i;
    rmask[kw * W + col] = w;
}

// ---------------------------------------------------------------------------
// K2: one block per (128-col tile, 32-row word-row) = 1024 blocks, 24 KB LDS.
// Decode: threads 0..191 each build one LDS column of f = d1^2 from 3 mask
// words (96-bit window; far-walk beyond +/-32 rows is essentially never).
// Row pass: thread (col=tid&127, rowhalf=tid>>7) does 16 rows:
//   fixed unrolled d=1..8 window (16 independent LDS loads, batched issue),
//   then early-exit d=9..32 only if best > 81 (rare), then exact global
//   fallback only if best > 33^2 (never for this input, exact for any).
// Writes sqrt(D) fp32 to out; one atomicMax per block.
// ---------------------------------------------------------------------------
__global__ void __launch_bounds__(NTHR)
k2_edt(const unsigned* __restrict__ rmask, float* __restrict__ dist,
       unsigned int* __restrict__ maxp) {
    __shared__ float ftile[32][LW];   // 24 KB
    __shared__ float smax[4];
    const int tid = threadIdx.x;
    const int c0 = blockIdx.x * TILE;
    const int ks = blockIdx.y;
    const int rbase = ks * 32;

    // ---- decode one column into LDS
    if (tid < LW) {
        int gc = c0 - HALO + tid;
        if (gc >= 0 && gc < W) {
            unsigned wm1 = (ks > 0)       ? rmask[(ks - 1) * W + gc] : 0u;
            unsigned w0  =                  rmask[ks * W + gc];
            unsigned wp1 = (ks < NWR - 1) ? rmask[(ks + 1) * W + gc] : 0u;
            u64 A  = (u64)wm1 | ((u64)w0 << 32);
            u64 Bv = (u64)w0  | ((u64)wp1 << 32);
#pragma unroll
            for (int i = 0; i < 32; ++i) {
                int p = 32 + i;
                u64 Am = A & ((1ull << p) - 1ull);
                int da = Am ? (p - (63 - __clzll(Am))) : vfar_up(rmask, gc, rbase + i, ks);
                u64 Bm = Bv >> (i + 1);
                int db = Bm ? __ffsll(Bm) : vfar_dn(rmask, gc, rbase + i, ks);
                int d1 = min(min(da, db), DCLAMP);
                float fd = (float)d1;
                ftile[i][tid] = ((w0 >> i) & 1u) ? 0.0f : fd * fd;
            }
        } else {
#pragma unroll
            for (int i = 0; i < 32; ++i)
                ftile[i][tid] = 1e9f;   // pad: cost >= 1e9 never wins
        }
    }
    __syncthreads();

    // ---- row pass: 16 rows per thread
    const int col = tid & (TILE - 1);
    const int rh  = tid >> 7;           // 0 or 1
    const int lj  = HALO + col;         // [32, 160); +/-32 stays in [0,192)
    const int jj  = c0 + col;
    float res[16];
    float lmax = 0.0f;
#pragma unroll 2
    for (int t = 0; t < 16; ++t) {
        const int i = rh * 16 + t;
        float best = ftile[i][lj];
#pragma unroll
        for (int d = 1; d <= 8; ++d) {   // independent loads -> batched issue
            float q = (float)(d * d);
            best = fminf(best, ftile[i][lj - d] + q);
            best = fminf(best, ftile[i][lj + d] + q);
        }
        if (81.0f < best) {              // rare: extend within LDS halo
            for (int d = 9; d <= HALO && (float)(d * d) < best; ++d) {
                float q = (float)(d * d);
                best = fminf(best, ftile[i][lj - d] + q);
                best = fminf(best, ftile[i][lj + d] + q);
            }
            if ((float)((HALO + 1) * (HALO + 1)) < best) {
                // exact global fallback (never taken for random 50% mask)
                int r = rbase + i;
                for (int d = HALO + 1; d < W && (float)(d * d) < best; ++d) {
                    float q = (float)(d * d);
                    int jm = jj - d, jp = jj + d;
                    if (jm >= 0) best = fminf(best, f_from_mask(rmask, jm, r) + q);
                    if (jp < W)  best = fminf(best, f_from_mask(rmask, jp, r) + q);
                }
            }
        }
        float rr = sqrtf(best);
        res[t] = rr;
        lmax = fmaxf(lmax, rr);
    }
#pragma unroll
    for (int t = 0; t < 16; ++t)
        dist[(size_t)(rbase + rh * 16 + t) * W + jj] = res[t];

    for (int o = 32; o > 0; o >>= 1) lmax = fmaxf(lmax, __shfl_down(lmax, o, 64));
    if ((tid & 63) == 0) smax[tid >> 6] = lmax;
    __syncthreads();
    if (tid == 0)
        atomicMax(maxp, __float_as_uint(fmaxf(fmaxf(smax[0], smax[1]),
                                              fmaxf(smax[2], smax[3]))));
}

// ---------------------------------------------------------------------------
// K3: in-place normalize, float4 -> int4 (uint8 semantics: trunc(d/m*255)).
// ---------------------------------------------------------------------------
__global__ void k3_norm(int* __restrict__ out, const unsigned int* __restrict__ maxp) {
    size_t idx = ((size_t)blockIdx.x * NTHR + threadIdx.x) * 4;
    float m = __uint_as_float(*maxp);
    float4 dv = *(const float4*)((const float*)out + idx);
    float r[4] = {dv.x, dv.y, dv.z, dv.w};
    int o[4];
#pragma unroll
    for (int k = 0; k < 4; ++k) {
        float v = (m > 0.0f) ? (r[k] / m * 255.0f) : r[k];  // numpy op order
        v = fminf(fmaxf(v, 0.0f), 255.0f);
        o[k] = (int)v;                                      // trunc, like astype(uint8)
    }
    *(int4*)(out + idx) = make_int4(o[0], o[1], o[2], o[3]);
}

extern "C" void kernel_launch(void* const* d_in, const int* in_sizes, int n_in,
                              void* d_out, int out_size, void* d_ws, size_t ws_size,
                              hipStream_t stream) {
    const float* img = (const float*)d_in[0];
    int* out = (int*)d_out;

    // ws: rmask 512 KB | maxp 4 B
    unsigned* rmask = (unsigned*)d_ws;
    unsigned int* maxp = (unsigned int*)((char*)d_ws + (size_t)NWR * W * 4);

    k1_pack<<<dim3(NWR * W / NTHR), dim3(NTHR), 0, stream>>>(img, rmask, maxp);
    k2_edt <<<dim3(W / TILE, NWR), dim3(NTHR), 0, stream>>>(rmask, (float*)out, maxp);
    k3_norm<<<dim3(H * W / (NTHR * 4)), dim3(NTHR), 0, stream>>>(out, maxp);
}

// Round 11
// 91.072 us; speedup vs baseline: 2.1161x; 1.0302x over previous
//
#include <hip/hip_runtime.h>
#include <math.h>

typedef unsigned long long u64;

#define H 2048
#define W 2048
#define NWR 64          // word-rows (H/32)
#define TILE 128        // output cols per K2 block
#define HALO 32         // LDS halo; register window covers d<=8, LDS d<=32, then global
#define LW 192          // TILE + 2*HALO
#define LSTRIDE 193     // odd stride: conflict-free column-major-ish access
#define DCLAMP 2900     // > max possible distance; f <= 8.41e6 exact in fp32
#define NTHR 256

// ---------------------------------------------------------------------------
// Far-walks on the background bitmask (rare; out-of-line to keep hot loop small)
// ---------------------------------------------------------------------------
__device__ __attribute__((noinline)) int vfar_up(const unsigned* rmask, int col, int r, int ks) {
    for (int kk = ks - 2; kk >= 0; --kk) {
        unsigned w = rmask[kk * W + col];
        if (w) return r - (kk * 32 + (31 - __clz(w)));
    }
    return DCLAMP;
}
__device__ __attribute__((noinline)) int vfar_dn(const unsigned* rmask, int col, int r, int ks) {
    for (int kk = ks + 2; kk < NWR; ++kk) {
        unsigned w = rmask[kk * W + col];
        if (w) return (kk * 32 + (__ffs(w) - 1)) - r;
    }
    return DCLAMP;
}

// exact f at arbitrary (r, col) straight from the bitmask (never-taken fallback)
__device__ __attribute__((noinline)) float f_from_mask(const unsigned* rmask, int col, int r) {
    int kw = r >> 5, b = r & 31;
    unsigned wm1 = (kw > 0)       ? rmask[(kw - 1) * W + col] : 0u;
    unsigned w0  =                  rmask[kw * W + col];
    unsigned wp1 = (kw < NWR - 1) ? rmask[(kw + 1) * W + col] : 0u;
    if ((w0 >> b) & 1u) return 0.0f;
    u64 A  = (u64)wm1 | ((u64)w0 << 32);
    u64 Bv = (u64)w0  | ((u64)wp1 << 32);
    int p = 32 + b;
    u64 Am = A & ((1ull << p) - 1ull);
    int da = Am ? (p - (63 - __clzll(Am))) : vfar_up(rmask, col, r, kw);
    u64 Bm = Bv >> (b + 1);
    int db = Bm ? __ffsll(Bm) : vfar_dn(rmask, col, r, kw);
    int d1 = min(min(da, db), DCLAMP);
    return (float)d1 * (float)d1;
}

// ---------------------------------------------------------------------------
// K1: pack background bits; one thread per mask word; coalesced.
// ---------------------------------------------------------------------------
__global__ void k1_pack(const float* __restrict__ img, unsigned* __restrict__ rmask,
                        unsigned int* __restrict__ maxp) {
    int gid = blockIdx.x * NTHR + threadIdx.x;
    if (gid == 0) *maxp = 0u;
    int col = gid & (W - 1);
    int kw  = gid >> 11;
    unsigned w = 0;
#pragma unroll
    for (int i = 0; i < 32; ++i)
        w |= (img[(size_t)(kw * 32 + i) * W + col] <= 0.5f ? 1u : 0u) << i;
    rmask[kw * W + col] = w;
}

// ---------------------------------------------------------------------------
// K2: block = (128-col tile, 32-row word-row), 1024 blocks, 24.7 KB LDS.
// Phase 1 (decode): threads 0..191 build f = d1^2 per column from 3 mask words.
// Phase 2 (row pass): thread (row=tid&31, strip=tid>>5): load 32 consecutive
//   f values (strip+/-8 halo) into REGISTERS (conflict-free b32, odd stride),
//   compute 16 outputs from regs only: best = min_{|d|<=8} reg[..] + d^2.
//   Rare: best>81 -> LDS halo d<=32; best>33^2 -> exact global walk (never
//   taken for this input; exact for any).
// Phase 3: stage results in LDS, fully-coalesced float4 store; block max ->
//   one atomicMax.
// ---------------------------------------------------------------------------
__global__ void __launch_bounds__(NTHR)
k2_edt(const unsigned* __restrict__ rmask, float* __restrict__ dist,
       unsigned int* __restrict__ maxp) {
    __shared__ float ftile[32][LSTRIDE];   // 24.7 KB
    __shared__ float smax[4];
    const int tid = threadIdx.x;
    const int c0 = blockIdx.x * TILE;
    const int ks = blockIdx.y;
    const int rbase = ks * 32;

    // ---- Phase 1: decode one column into LDS
    if (tid < LW) {
        int gc = c0 - HALO + tid;
        if (gc >= 0 && gc < W) {
            unsigned wm1 = (ks > 0)       ? rmask[(ks - 1) * W + gc] : 0u;
            unsigned w0  =                  rmask[ks * W + gc];
            unsigned wp1 = (ks < NWR - 1) ? rmask[(ks + 1) * W + gc] : 0u;
            u64 A  = (u64)wm1 | ((u64)w0 << 32);
            u64 Bv = (u64)w0  | ((u64)wp1 << 32);
#pragma unroll
            for (int i = 0; i < 32; ++i) {
                int p = 32 + i;
                u64 Am = A & ((1ull << p) - 1ull);
                int da = Am ? (p - (63 - __clzll(Am))) : vfar_up(rmask, gc, rbase + i, ks);
                u64 Bm = Bv >> (i + 1);
                int db = Bm ? __ffsll(Bm) : vfar_dn(rmask, gc, rbase + i, ks);
                int d1 = min(min(da, db), DCLAMP);
                float fd = (float)d1;
                ftile[i][tid] = ((w0 >> i) & 1u) ? 0.0f : fd * fd;
            }
        } else {
#pragma unroll
            for (int i = 0; i < 32; ++i)
                ftile[i][tid] = 1e9f;   // pad: cost >= 1e9 never wins
        }
    }
    __syncthreads();

    // ---- Phase 2: register sliding window
    const int i  = tid & 31;        // row within tile
    const int p  = tid >> 5;        // 16-col strip
    const int lc = HALO + p * 16;   // LDS col of first output
    float reg[32];                  // f for LDS cols lc-8 .. lc+23
#pragma unroll
    for (int k = 0; k < 32; ++k)
        reg[k] = ftile[i][lc - 8 + k];

    float res[16];
    float lmax = 0.0f;
#pragma unroll
    for (int m = 0; m < 16; ++m) {
        float best = reg[m + 8];
#pragma unroll
        for (int d = 1; d <= 8; ++d) {
            float q = (float)(d * d);
            best = fminf(best, reg[m + 8 - d] + q);
            best = fminf(best, reg[m + 8 + d] + q);
        }
        if (__builtin_expect(81.0f < best, 0)) {
            // extend within LDS halo (rare)
            for (int d = 9; d <= HALO && (float)(d * d) < best; ++d) {
                float q = (float)(d * d);
                best = fminf(best, ftile[i][lc + m - d] + q);
                best = fminf(best, ftile[i][lc + m + d] + q);
            }
            if ((float)((HALO + 1) * (HALO + 1)) < best) {
                // exact global fallback (never taken for random 50% mask)
                int r = rbase + i, jj = c0 + p * 16 + m;
                for (int d = HALO + 1; d < W && (float)(d * d) < best; ++d) {
                    float q = (float)(d * d);
                    int jm = jj - d, jp = jj + d;
                    if (jm >= 0) best = fminf(best, f_from_mask(rmask, jm, r) + q);
                    if (jp < W)  best = fminf(best, f_from_mask(rmask, jp, r) + q);
                }
            }
        }
        float rr = sqrtf(best);
        res[m] = rr;
        lmax = fmaxf(lmax, rr);
    }

    // ---- Phase 3: stage to LDS, coalesced store
    __syncthreads();   // all reads of ftile done
#pragma unroll
    for (int m = 0; m < 16; ++m)
        ftile[i][p * 16 + m] = res[m];
    __syncthreads();
#pragma unroll
    for (int q = 0; q < 4; ++q) {
        int r  = (tid >> 5) + 8 * q;      // 0..31
        int c4 = (tid & 31) * 4;
        float4 v = make_float4(ftile[r][c4], ftile[r][c4 + 1],
                               ftile[r][c4 + 2], ftile[r][c4 + 3]);
        *(float4*)(dist + (size_t)(rbase + r) * W + c0 + c4) = v;
    }

    for (int o = 32; o > 0; o >>= 1) lmax = fmaxf(lmax, __shfl_down(lmax, o, 64));
    if ((tid & 63) == 0) smax[tid >> 6] = lmax;
    __syncthreads();
    if (tid == 0)
        atomicMax(maxp, __float_as_uint(fmaxf(fmaxf(smax[0], smax[1]),
                                              fmaxf(smax[2], smax[3]))));
}

// ---------------------------------------------------------------------------
// K3: in-place normalize, float4 -> int4 (uint8 semantics: trunc(d/m*255)).
// ---------------------------------------------------------------------------
__global__ void k3_norm(int* __restrict__ out, const unsigned int* __restrict__ maxp) {
    size_t idx = ((size_t)blockIdx.x * NTHR + threadIdx.x) * 4;
    float m = __uint_as_float(*maxp);
    float4 dv = *(const float4*)((const float*)out + idx);
    float r[4] = {dv.x, dv.y, dv.z, dv.w};
    int o[4];
#pragma unroll
    for (int k = 0; k < 4; ++k) {
        float v = (m > 0.0f) ? (r[k] / m * 255.0f) : r[k];  // numpy op order
        v = fminf(fmaxf(v, 0.0f), 255.0f);
        o[k] = (int)v;                                      // trunc, like astype(uint8)
    }
    *(int4*)(out + idx) = make_int4(o[0], o[1], o[2], o[3]);
}

extern "C" void kernel_launch(void* const* d_in, const int* in_sizes, int n_in,
                              void* d_out, int out_size, void* d_ws, size_t ws_size,
                              hipStream_t stream) {
    const float* img = (const float*)d_in[0];
    int* out = (int*)d_out;

    // ws: rmask 512 KB | maxp 4 B
    unsigned* rmask = (unsigned*)d_ws;
    unsigned int* maxp = (unsigned int*)((char*)d_ws + (size_t)NWR * W * 4);

    k1_pack<<<dim3(NWR * W / NTHR), dim3(NTHR), 0, stream>>>(img, rmask, maxp);
    k2_edt <<<dim3(W / TILE, NWR), dim3(NTHR), 0, stream>>>(rmask, (float*)out, maxp);
    k3_norm<<<dim3(H * W / (NTHR * 4)), dim3(NTHR), 0, stream>>>(out, maxp);
}